// Round 14
// baseline (295.031 us; speedup 1.0000x reference)
//
#include <hip/hip_runtime.h>
#include <hip/hip_bf16.h>
#include <math.h>

#define H 256
#define F 512
#define E 8
#define T_TOK 32768
#define BM 64    // tokens per block -> grid 512 -> 2 blocks/CU
#define FC 64    // F-chunk size
#define NCH 64   // E * F/FC chunks

typedef float    f32x4 __attribute__((__ext_vector_type__(4)));
typedef _Float16 f16x8 __attribute__((__ext_vector_type__(8)));
typedef _Float16 f16x4 __attribute__((__ext_vector_type__(4)));

// lgkm-only barrier: publishes LDS (hs); register global loads stay in flight
#define BAR_LG() asm volatile("s_waitcnt lgkmcnt(0)\ns_barrier" ::: "memory")

// gelu(v) = v - v * rcp(1 + exp2(v*(c1 + c2*v^2)))   [tanh-approx]
__device__ __forceinline__ float gelu_fast(float v) {
    const float c1 = 2.302117236f;
    const float c2 = 0.102943842f;
    float u2 = v * fmaf(c2, v * v, c1);
    float ex = __builtin_amdgcn_exp2f(u2);
    float r = __builtin_amdgcn_rcpf(ex + 1.0f);
    return v - v * r;
}

// W1[e][h][f] fp32 -> W1p packed GEMM1 A-fragments.  (R11-proven, unchanged)
// block blk = s*2 + fw  (s = e*8+c). frag g = ks*128 + pair*64 + lane.
// value[d] = W1[e][ks*32 + (lane>>4)*8 + d][c*64 + fw*32 + pair*16 + (lane&15)]
__global__ void prep_w1p(const float* __restrict__ in, _Float16* __restrict__ out) {
    __shared__ float t[256][33];
    int blk = blockIdx.x;          // 128
    int s = blk >> 1, fw = blk & 1;
    int e = s >> 3, c = s & 7;
    int f0 = c * 64 + fw * 32;
    int tid = threadIdx.x;         // 256
    int hr = tid >> 3, q = tid & 7;
#pragma unroll
    for (int pp = 0; pp < 8; ++pp) {
        int h = pp * 32 + hr;
        float4 v = *(const float4*)(in + ((size_t)e * H + h) * F + f0 + q * 4);
        t[h][q * 4 + 0] = v.x;
        t[h][q * 4 + 1] = v.y;
        t[h][q * 4 + 2] = v.z;
        t[h][q * 4 + 3] = v.w;
    }
    __syncthreads();
#pragma unroll
    for (int r = 0; r < 4; ++r) {
        int g = r * 256 + tid;
        int ks = g >> 7, pair = (g >> 6) & 1, ln = g & 63;
        int l4v = ln >> 4, l15v = ln & 15;
        f16x8 v;
#pragma unroll
        for (int d = 0; d < 8; ++d) v[d] = (_Float16)t[ks * 32 + l4v * 8 + d][pair * 16 + l15v];
        *(f16x8*)(out + ((size_t)blk * 1024 + g) * 8) = v;
    }
}

// W2[e][f][h] fp32 -> W2p packed GEMM2 A-fragments.  (R11-proven, unchanged)
// chunk s=e*8+c; G = (hw*8 + i*2 + ks)*64 + lane
// value[d] = W2[e][c*64 + ks*32 + (lane>>4)*8 + d][hw*64 + i*16 + (lane&15)]
__global__ void prep_w2p(const float* __restrict__ in, _Float16* __restrict__ out) {
    __shared__ float t[64][65];
    int blk = blockIdx.x;         // 256
    int s = blk >> 2, hw = blk & 3;
    int e = s >> 3, c = s & 7;
    int tid = threadIdx.x;
    int fl = tid >> 2, h16 = (tid & 3) * 16;
    const float* ip = in + ((size_t)(e * F + c * 64 + fl)) * H + hw * 64 + h16;
#pragma unroll
    for (int q = 0; q < 4; ++q) {
        float4 v = *(const float4*)(ip + q * 4);
        t[fl][h16 + q * 4 + 0] = v.x;
        t[fl][h16 + q * 4 + 1] = v.y;
        t[fl][h16 + q * 4 + 2] = v.z;
        t[fl][h16 + q * 4 + 3] = v.w;
    }
    __syncthreads();
#pragma unroll
    for (int r = 0; r < 2; ++r) {
        int g = tid * 2 + r;
        int lane = g & 63, iks = g >> 6;
        int fb = (iks & 1) * 32 + (lane >> 4) * 8;
        int hl = (iks >> 1) * 16 + (lane & 15);
        f16x8 v;
#pragma unroll
        for (int d = 0; d < 8; ++d) v[d] = (_Float16)t[fb + d][hl];
        *(f16x8*)(out + (size_t)s * 16384 + ((size_t)hw * 512 + g) * 8) = v;
    }
}

__global__ void gate_kernel(const float* __restrict__ x, const float* __restrict__ Wg,
                            const float* __restrict__ bg, float* __restrict__ probs) {
    int gid = blockIdx.x * blockDim.x + threadIdx.x;
    int t = gid >> 3, e = gid & 7;
    const float* xr = x + (size_t)t * H;
    float acc = 0.f;
    for (int k = 0; k < H; k += 4) {
        float4 xv = *(const float4*)(xr + k);
        acc += xv.x * Wg[(k + 0) * E + e] + xv.y * Wg[(k + 1) * E + e]
             + xv.z * Wg[(k + 2) * E + e] + xv.w * Wg[(k + 3) * E + e];
    }
    acc += bg[e];
    float m = acc;
    for (int s = 1; s < 8; s <<= 1) m = fmaxf(m, __shfl_xor(m, s, 8));
    float p = expf(acc - m);
    float sum = p;
    for (int s = 1; s < 8; s <<= 1) sum += __shfl_xor(sum, s, 8);
    probs[gid] = p / sum;
}

// ---- main: R11 region skeleton (immediate GEMM2, 1x BAR_LG) at BM=64, 2 blocks/CU
__global__ __launch_bounds__(512, 4) void moe_main(
    const float* __restrict__ x, const _Float16* __restrict__ W1p,
    const float* __restrict__ b1, const _Float16* __restrict__ W2p,
    const float* __restrict__ b2, const float* __restrict__ probs,
    float* __restrict__ out) {

    __shared__ __align__(16) _Float16 hs[2][BM * FC];  // 2 x 8 KB (16 KB total)

    int tid = threadIdx.x;
    int lane = tid & 63, wid = tid >> 6;
    int t0 = blockIdx.x * BM;
    int l15 = lane & 15, l4 = lane >> 4;

    int fw = wid >> 2, tw1 = wid & 3;   // GEMM1: 2(f-32) x 4(tok-16)
    int hw = wid >> 1, tw2 = wid & 1;   // GEMM2: 4(h-64) x 2(tok-32)

    // x B-fragments in registers: one token row per lane, all of H (32 VGPR)
    f16x8 xf[8];
    {
        const float* xr = x + (size_t)(t0 + tw1 * 16 + l15) * H + (l4 << 3);
#pragma unroll
        for (int ks = 0; ks < 8; ++ks) {
            float4 v0 = *(const float4*)(xr + ks * 32);
            float4 v1 = *(const float4*)(xr + ks * 32 + 4);
            f16x8 hv;
            hv[0] = (_Float16)v0.x; hv[1] = (_Float16)v0.y; hv[2] = (_Float16)v0.z; hv[3] = (_Float16)v0.w;
            hv[4] = (_Float16)v1.x; hv[5] = (_Float16)v1.y; hv[6] = (_Float16)v1.z; hv[7] = (_Float16)v1.w;
            xf[ks] = hv;
        }
    }
    // gate probs for this wave's GEMM1 token row, all experts
    float pg[8];
    {
        const float* pp = probs + (size_t)(t0 + tw1 * 16 + l15) * E;
        float4 p0 = *(const float4*)pp, p1 = *(const float4*)(pp + 4);
        pg[0] = p0.x; pg[1] = p0.y; pg[2] = p0.z; pg[3] = p0.w;
        pg[4] = p1.x; pg[5] = p1.y; pg[6] = p1.z; pg[7] = p1.w;
    }

    f32x4 yacc[4][2];
#pragma unroll
    for (int i = 0; i < 4; ++i)
#pragma unroll
        for (int j = 0; j < 2; ++j) yacc[i][j] = (f32x4){0.f, 0.f, 0.f, 0.f};

    for (int s = 0; s < NCH; ++s) {
        int b = s & 1;
        int e = s >> 3, c = s & 7, fbase = c * FC;

        // (1) av: packed W2 fragments for THIS chunk (L1/L2-hot, coalesced)
        f16x8 av[4][2];
        {
            const _Float16* wb = W2p + (size_t)s * 16384 + ((size_t)(hw * 8) * 64 + lane) * 8;
#pragma unroll
            for (int i = 0; i < 4; ++i) {
                av[i][0] = *(const f16x8*)(wb + (i * 2 + 0) * 512);
                av[i][1] = *(const f16x8*)(wb + (i * 2 + 1) * 512);
            }
        }
        float4 bvq[2];
#pragma unroll
        for (int i = 0; i < 2; ++i)
            bvq[i] = *(const float4*)(b1 + (size_t)e * F + fbase + (fw * 2 + i) * 16 + l4 * 4);

        // (2) GEMM1: W1 frags streamed in two 4-ks batches (R11-proven path)
        const _Float16* w1b = W1p + ((size_t)(s * 2 + fw) * 1024 + lane) * 8;
        f16x8 w1a[4][2];
#pragma unroll
        for (int ks = 0; ks < 4; ++ks) {
            w1a[ks][0] = *(const f16x8*)(w1b + (ks * 2 + 0) * 512);
            w1a[ks][1] = *(const f16x8*)(w1b + (ks * 2 + 1) * 512);
        }
        f32x4 hacc[2];
        hacc[0] = hacc[1] = (f32x4){0.f, 0.f, 0.f, 0.f};
#pragma unroll
        for (int ks = 0; ks < 4; ++ks) {
            hacc[0] = __builtin_amdgcn_mfma_f32_16x16x32_f16(w1a[ks][0], xf[ks], hacc[0], 0, 0, 0);
            hacc[1] = __builtin_amdgcn_mfma_f32_16x16x32_f16(w1a[ks][1], xf[ks], hacc[1], 0, 0, 0);
        }
#pragma unroll
        for (int ks = 0; ks < 4; ++ks) {
            w1a[ks][0] = *(const f16x8*)(w1b + ((ks + 4) * 2 + 0) * 512);
            w1a[ks][1] = *(const f16x8*)(w1b + ((ks + 4) * 2 + 1) * 512);
        }
#pragma unroll
        for (int ks = 0; ks < 4; ++ks) {
            hacc[0] = __builtin_amdgcn_mfma_f32_16x16x32_f16(w1a[ks][0], xf[ks + 4], hacc[0], 0, 0, 0);
            hacc[1] = __builtin_amdgcn_mfma_f32_16x16x32_f16(w1a[ks][1], xf[ks + 4], hacc[1], 0, 0, 0);
        }

        // (3) GELU + gate-fold -> hs[b]
        float p = pg[e];
#pragma unroll
        for (int i = 0; i < 2; ++i) {
            int flocal = (fw * 2 + i) * 16 + l4 * 4;
            float4 bv = bvq[i];
            int tokl = tw1 * 16 + l15;
            f16x4 hp;
            hp[0] = (_Float16)(p * gelu_fast(hacc[i][0] + bv.x));
            hp[1] = (_Float16)(p * gelu_fast(hacc[i][1] + bv.y));
            hp[2] = (_Float16)(p * gelu_fast(hacc[i][2] + bv.z));
            hp[3] = (_Float16)(p * gelu_fast(hacc[i][3] + bv.w));
            int idx = (tokl * FC + flocal) ^ ((tokl & 7) << 3);
            *(f16x4*)&hs[b][idx] = hp;
        }

        // (4) the one barrier: hs[b] published (lgkm only)
        BAR_LG();

        // (5) immediate GEMM2: y += W2chunk . hs[b]^T, K=FC (av in regs)
#pragma unroll
        for (int ks = 0; ks < FC / 32; ++ks) {
            int kidx = ks * 32 + (l4 << 3);
            f16x8 bv2[2];
#pragma unroll
            for (int j = 0; j < 2; ++j) {
                int tok = tw2 * 32 + j * 16 + l15;
                bv2[j] = *(const f16x8*)&hs[b][(tok * FC + kidx) ^ ((tok & 7) << 3)];
            }
#pragma unroll
            for (int i = 0; i < 4; ++i)
#pragma unroll
                for (int j = 0; j < 2; ++j)
                    yacc[i][j] = __builtin_amdgcn_mfma_f32_16x16x32_f16(av[i][ks], bv2[j], yacc[i][j], 0, 0, 0);
        }
        // hs[b] next rewritten in region s+2, after BAR(s+1) — reads retired by then
    }

    // epilogue: out = yacc + sum_e p_e * b2_e
#pragma unroll
    for (int j = 0; j < 2; ++j) {
        int tok = t0 + tw2 * 32 + j * 16 + l15;
        float pe[8];
#pragma unroll
        for (int e = 0; e < 8; ++e) pe[e] = probs[(size_t)tok * E + e];
#pragma unroll
        for (int i = 0; i < 4; ++i) {
            int h0 = hw * 64 + i * 16 + l4 * 4;
            f32x4 acc = yacc[i][j];
#pragma unroll
            for (int e = 0; e < 8; ++e) {
                float4 b2v = *(const float4*)(b2 + (size_t)e * H + h0);
                acc[0] += pe[e] * b2v.x;
                acc[1] += pe[e] * b2v.y;
                acc[2] += pe[e] * b2v.z;
                acc[3] += pe[e] * b2v.w;
            }
            *(f32x4*)(out + (size_t)tok * H + h0) = acc;
        }
    }
}

extern "C" void kernel_launch(void* const* d_in, const int* in_sizes, int n_in,
                              void* d_out, int out_size, void* d_ws, size_t ws_size,
                              hipStream_t stream) {
    const float* x  = (const float*)d_in[0];
    const float* Wg = (const float*)d_in[1];
    const float* bg = (const float*)d_in[2];
    const float* W1 = (const float*)d_in[3];
    const float* b1 = (const float*)d_in[4];
    const float* W2 = (const float*)d_in[5];
    const float* b2 = (const float*)d_in[6];
    float* out = (float*)d_out;

    _Float16* W1p = (_Float16*)d_ws;                       // packed GEMM1 frags, 2 MB
    _Float16* W2p = W1p + (size_t)E * F * H;               // packed GEMM2 frags, 2 MB
    float* probs  = (float*)(W2p + (size_t)64 * 16384);    // [T][E] fp32, 1 MB

    prep_w1p<<<128, 256, 0, stream>>>(W1, W1p);
    prep_w2p<<<256, 256, 0, stream>>>(W2, W2p);
    gate_kernel<<<(T_TOK * E) / 256, 256, 0, stream>>>(x, Wg, bg, probs);
    moe_main<<<T_TOK / BM, 512, 0, stream>>>(x, W1p, b1, W2p, b2, probs, out);
}

// Round 17
// 221.713 us; speedup vs baseline: 1.3307x; 1.3307x over previous
//
#include <hip/hip_runtime.h>
#include <hip/hip_bf16.h>
#include <math.h>

#define H 256
#define F 512
#define E 8
#define T_TOK 32768
#define BM 128   // tokens per block
#define FC 64    // F-chunk size
#define NCH 64   // E * F/FC chunks

typedef float    f32x4 __attribute__((__ext_vector_type__(4)));
typedef _Float16 f16x8 __attribute__((__ext_vector_type__(8)));
typedef _Float16 f16x4 __attribute__((__ext_vector_type__(4)));

// lgkm-only barrier: publishes LDS (hs); register global loads stay in flight
#define BAR_LG() asm volatile("s_waitcnt lgkmcnt(0)\ns_barrier" ::: "memory")

// gelu(v) = v - v * rcp(1 + exp2(v*(c1 + c2*v^2)))   [tanh-approx]
__device__ __forceinline__ float gelu_fast(float v) {
    const float c1 = 2.302117236f;
    const float c2 = 0.102943842f;
    float u2 = v * fmaf(c2, v * v, c1);
    float ex = __builtin_amdgcn_exp2f(u2);
    float r = __builtin_amdgcn_rcpf(ex + 1.0f);
    return v - v * r;
}

// W1[e][h][f] fp32 -> W1p packed GEMM1 A-fragments.  (R11-proven, unchanged)
// block blk = s*2 + fw  (s = e*8+c). frag g = ks*128 + pair*64 + lane.
// value[d] = W1[e][ks*32 + (lane>>4)*8 + d][c*64 + fw*32 + pair*16 + (lane&15)]
__global__ void prep_w1p(const float* __restrict__ in, _Float16* __restrict__ out) {
    __shared__ float t[256][33];
    int blk = blockIdx.x;          // 128
    int s = blk >> 1, fw = blk & 1;
    int e = s >> 3, c = s & 7;
    int f0 = c * 64 + fw * 32;
    int tid = threadIdx.x;         // 256
    int hr = tid >> 3, q = tid & 7;
#pragma unroll
    for (int pp = 0; pp < 8; ++pp) {
        int h = pp * 32 + hr;
        float4 v = *(const float4*)(in + ((size_t)e * H + h) * F + f0 + q * 4);
        t[h][q * 4 + 0] = v.x;
        t[h][q * 4 + 1] = v.y;
        t[h][q * 4 + 2] = v.z;
        t[h][q * 4 + 3] = v.w;
    }
    __syncthreads();
#pragma unroll
    for (int r = 0; r < 4; ++r) {
        int g = r * 256 + tid;
        int ks = g >> 7, pair = (g >> 6) & 1, ln = g & 63;
        int l4v = ln >> 4, l15v = ln & 15;
        f16x8 v;
#pragma unroll
        for (int d = 0; d < 8; ++d) v[d] = (_Float16)t[ks * 32 + l4v * 8 + d][pair * 16 + l15v];
        *(f16x8*)(out + ((size_t)blk * 1024 + g) * 8) = v;
    }
}

// W2[e][f][h] fp32 -> W2p packed GEMM2 A-fragments.  (R11-proven, unchanged)
// chunk s=e*8+c; G = (hw*8 + i*2 + ks)*64 + lane
// value[d] = W2[e][c*64 + ks*32 + (lane>>4)*8 + d][hw*64 + i*16 + (lane&15)]
__global__ void prep_w2p(const float* __restrict__ in, _Float16* __restrict__ out) {
    __shared__ float t[64][65];
    int blk = blockIdx.x;         // 256
    int s = blk >> 2, hw = blk & 3;
    int e = s >> 3, c = s & 7;
    int tid = threadIdx.x;
    int fl = tid >> 2, h16 = (tid & 3) * 16;
    const float* ip = in + ((size_t)(e * F + c * 64 + fl)) * H + hw * 64 + h16;
#pragma unroll
    for (int q = 0; q < 4; ++q) {
        float4 v = *(const float4*)(ip + q * 4);
        t[fl][h16 + q * 4 + 0] = v.x;
        t[fl][h16 + q * 4 + 1] = v.y;
        t[fl][h16 + q * 4 + 2] = v.z;
        t[fl][h16 + q * 4 + 3] = v.w;
    }
    __syncthreads();
#pragma unroll
    for (int r = 0; r < 2; ++r) {
        int g = tid * 2 + r;
        int lane = g & 63, iks = g >> 6;
        int fb = (iks & 1) * 32 + (lane >> 4) * 8;
        int hl = (iks >> 1) * 16 + (lane & 15);
        f16x8 v;
#pragma unroll
        for (int d = 0; d < 8; ++d) v[d] = (_Float16)t[fb + d][hl];
        *(f16x8*)(out + (size_t)s * 16384 + ((size_t)hw * 512 + g) * 8) = v;
    }
}

__global__ void gate_kernel(const float* __restrict__ x, const float* __restrict__ Wg,
                            const float* __restrict__ bg, float* __restrict__ probs) {
    int gid = blockIdx.x * blockDim.x + threadIdx.x;
    int t = gid >> 3, e = gid & 7;
    const float* xr = x + (size_t)t * H;
    float acc = 0.f;
    for (int k = 0; k < H; k += 4) {
        float4 xv = *(const float4*)(xr + k);
        acc += xv.x * Wg[(k + 0) * E + e] + xv.y * Wg[(k + 1) * E + e]
             + xv.z * Wg[(k + 2) * E + e] + xv.w * Wg[(k + 3) * E + e];
    }
    acc += bg[e];
    float m = acc;
    for (int s = 1; s < 8; s <<= 1) m = fmaxf(m, __shfl_xor(m, s, 8));
    float p = expf(acc - m);
    float sum = p;
    for (int s = 1; s < 8; s <<= 1) sum += __shfl_xor(sum, s, 8);
    probs[gid] = p / sum;
}

// ---- main: R11 structure verbatim + s_setprio around MFMA clusters (T5)
__global__ __launch_bounds__(512, 2) void moe_main(
    const float* __restrict__ x, const _Float16* __restrict__ W1p,
    const float* __restrict__ b1, const _Float16* __restrict__ W2p,
    const float* __restrict__ b2, const float* __restrict__ probs,
    float* __restrict__ out) {

    __shared__ __align__(16) _Float16 hs[2][BM * FC];  // 2 x 16 KB (32 KB total)

    int tid = threadIdx.x;
    int lane = tid & 63, wid = tid >> 6;
    int t0 = blockIdx.x * BM;
    int l15 = lane & 15, l4 = lane >> 4;

    int fw = wid >> 2, tw1 = wid & 3;   // GEMM1: 2(f-32) x 4(tok-32)
    int hw = wid >> 1, tw2 = wid & 1;   // GEMM2: 4(h-64) x 2(tok-64)

    // x B-fragments in registers (64 VGPR)
    f16x8 xf[8][2];
#pragma unroll
    for (int j = 0; j < 2; ++j) {
        const float* xr = x + (size_t)(t0 + tw1 * 32 + j * 16 + l15) * H + (l4 << 3);
#pragma unroll
        for (int ks = 0; ks < 8; ++ks) {
            float4 v0 = *(const float4*)(xr + ks * 32);
            float4 v1 = *(const float4*)(xr + ks * 32 + 4);
            f16x8 hv;
            hv[0] = (_Float16)v0.x; hv[1] = (_Float16)v0.y; hv[2] = (_Float16)v0.z; hv[3] = (_Float16)v0.w;
            hv[4] = (_Float16)v1.x; hv[5] = (_Float16)v1.y; hv[6] = (_Float16)v1.z; hv[7] = (_Float16)v1.w;
            xf[ks][j] = hv;
        }
    }

    f32x4 yacc[4][4];
#pragma unroll
    for (int i = 0; i < 4; ++i)
#pragma unroll
        for (int j = 0; j < 4; ++j) yacc[i][j] = (f32x4){0.f, 0.f, 0.f, 0.f};

    float p0g = 0.f, p1g = 0.f;

    for (int s = 0; s < NCH; ++s) {
        int b = s & 1;
        int e = s >> 3, c = s & 7, fbase = c * FC;

        if ((s & 7) == 0) {  // new expert: reload gate probs for this wave's tok rows
            p0g = probs[(size_t)(t0 + tw1 * 32 + l15) * E + e];
            p1g = probs[(size_t)(t0 + tw1 * 32 + 16 + l15) * E + e];
        }

        const _Float16* w1b = W1p + ((size_t)(s * 2 + fw) * 1024 + lane) * 8;

        // (1) W1 fragment batch 1 (ks 0..3) + av (GEMM2 A) + b1 — all L2/L1-hot
        f16x8 w1a[4][2];
#pragma unroll
        for (int ks = 0; ks < 4; ++ks) {
            w1a[ks][0] = *(const f16x8*)(w1b + (ks * 2 + 0) * 512);
            w1a[ks][1] = *(const f16x8*)(w1b + (ks * 2 + 1) * 512);
        }
        f16x8 av[4][2];
        {
            const _Float16* wb = W2p + (size_t)s * 16384 + ((size_t)(hw * 8) * 64 + lane) * 8;
#pragma unroll
            for (int i = 0; i < 4; ++i) {
                av[i][0] = *(const f16x8*)(wb + (i * 2 + 0) * 512);
                av[i][1] = *(const f16x8*)(wb + (i * 2 + 1) * 512);
            }
        }
        float4 bvq[2];
#pragma unroll
        for (int i = 0; i < 2; ++i)
            bvq[i] = *(const float4*)(b1 + (size_t)e * F + fbase + (fw * 2 + i) * 16 + l4 * 4);

        // (2) GEMM1 part 1 (ks 0..3), then stream batch 2 (ks 4..7), part 2
        f32x4 hacc[2][2];
        hacc[0][0] = hacc[0][1] = hacc[1][0] = hacc[1][1] = (f32x4){0.f, 0.f, 0.f, 0.f};
        __builtin_amdgcn_s_setprio(1);
#pragma unroll
        for (int ks = 0; ks < 4; ++ks) {
            hacc[0][0] = __builtin_amdgcn_mfma_f32_16x16x32_f16(w1a[ks][0], xf[ks][0], hacc[0][0], 0, 0, 0);
            hacc[0][1] = __builtin_amdgcn_mfma_f32_16x16x32_f16(w1a[ks][0], xf[ks][1], hacc[0][1], 0, 0, 0);
            hacc[1][0] = __builtin_amdgcn_mfma_f32_16x16x32_f16(w1a[ks][1], xf[ks][0], hacc[1][0], 0, 0, 0);
            hacc[1][1] = __builtin_amdgcn_mfma_f32_16x16x32_f16(w1a[ks][1], xf[ks][1], hacc[1][1], 0, 0, 0);
        }
        __builtin_amdgcn_s_setprio(0);
#pragma unroll
        for (int ks = 0; ks < 4; ++ks) {
            w1a[ks][0] = *(const f16x8*)(w1b + ((ks + 4) * 2 + 0) * 512);
            w1a[ks][1] = *(const f16x8*)(w1b + ((ks + 4) * 2 + 1) * 512);
        }
        __builtin_amdgcn_s_setprio(1);
#pragma unroll
        for (int ks = 0; ks < 4; ++ks) {
            hacc[0][0] = __builtin_amdgcn_mfma_f32_16x16x32_f16(w1a[ks][0], xf[ks + 4][0], hacc[0][0], 0, 0, 0);
            hacc[0][1] = __builtin_amdgcn_mfma_f32_16x16x32_f16(w1a[ks][0], xf[ks + 4][1], hacc[0][1], 0, 0, 0);
            hacc[1][0] = __builtin_amdgcn_mfma_f32_16x16x32_f16(w1a[ks][1], xf[ks + 4][0], hacc[1][0], 0, 0, 0);
            hacc[1][1] = __builtin_amdgcn_mfma_f32_16x16x32_f16(w1a[ks][1], xf[ks + 4][1], hacc[1][1], 0, 0, 0);
        }
        __builtin_amdgcn_s_setprio(0);

        // (3) GELU + gate-fold -> hs[b]
#pragma unroll
        for (int i = 0; i < 2; ++i) {
            int flocal = (fw * 2 + i) * 16 + l4 * 4;
            float4 bv = bvq[i];
#pragma unroll
            for (int j = 0; j < 2; ++j) {
                int tokl = tw1 * 32 + j * 16 + l15;
                float p = j ? p1g : p0g;
                f32x4 hv = hacc[i][j];
                f16x4 hp;
                hp[0] = (_Float16)(p * gelu_fast(hv[0] + bv.x));
                hp[1] = (_Float16)(p * gelu_fast(hv[1] + bv.y));
                hp[2] = (_Float16)(p * gelu_fast(hv[2] + bv.z));
                hp[3] = (_Float16)(p * gelu_fast(hv[3] + bv.w));
                int idx = (tokl * FC + flocal) ^ ((tokl & 7) << 3);
                *(f16x4*)&hs[b][idx] = hp;
            }
        }

        // (4) the one barrier: hs[b] published (lgkm only; reg loads stay in flight)
        BAR_LG();

        // (5) GEMM2: y += W2chunk . hs[b]^T, K=FC (av in regs)
        __builtin_amdgcn_s_setprio(1);
#pragma unroll
        for (int ks = 0; ks < FC / 32; ++ks) {
            int kidx = ks * 32 + (l4 << 3);
            f16x8 bv2[4];
#pragma unroll
            for (int j = 0; j < 4; ++j) {
                int tok = tw2 * 64 + j * 16 + l15;
                bv2[j] = *(const f16x8*)&hs[b][(tok * FC + kidx) ^ ((tok & 7) << 3)];
            }
#pragma unroll
            for (int i = 0; i < 4; ++i)
#pragma unroll
                for (int j = 0; j < 4; ++j)
                    yacc[i][j] = __builtin_amdgcn_mfma_f32_16x16x32_f16(av[i][ks], bv2[j], yacc[i][j], 0, 0, 0);
        }
        __builtin_amdgcn_s_setprio(0);
        // next region writes hs[b^1]; hs[b] next written at s+2, after BAR(s+1) — safe
    }

    // epilogue: out = yacc + sum_e p_e * b2_e
#pragma unroll
    for (int j = 0; j < 4; ++j) {
        int tok = t0 + tw2 * 64 + j * 16 + l15;
        float pe[8];
#pragma unroll
        for (int e = 0; e < 8; ++e) pe[e] = probs[(size_t)tok * E + e];
#pragma unroll
        for (int i = 0; i < 4; ++i) {
            int h0 = hw * 64 + i * 16 + l4 * 4;
            f32x4 acc = yacc[i][j];
#pragma unroll
            for (int e = 0; e < 8; ++e) {
                float4 b2v = *(const float4*)(b2 + (size_t)e * H + h0);
                acc[0] += pe[e] * b2v.x;
                acc[1] += pe[e] * b2v.y;
                acc[2] += pe[e] * b2v.z;
                acc[3] += pe[e] * b2v.w;
            }
            *(f32x4*)(out + (size_t)tok * H + h0) = acc;
        }
    }
}

extern "C" void kernel_launch(void* const* d_in, const int* in_sizes, int n_in,
                              void* d_out, int out_size, void* d_ws, size_t ws_size,
                              hipStream_t stream) {
    const float* x  = (const float*)d_in[0];
    const float* Wg = (const float*)d_in[1];
    const float* bg = (const float*)d_in[2];
    const float* W1 = (const float*)d_in[3];
    const float* b1 = (const float*)d_in[4];
    const float* W2 = (const float*)d_in[5];
    const float* b2 = (const float*)d_in[6];
    float* out = (float*)d_out;

    _Float16* W1p = (_Float16*)d_ws;                       // packed GEMM1 frags, 2 MB
    _Float16* W2p = W1p + (size_t)E * F * H;               // packed GEMM2 frags, 2 MB
    float* probs  = (float*)(W2p + (size_t)64 * 16384);    // [T][E] fp32, 1 MB

    prep_w1p<<<128, 256, 0, stream>>>(W1, W1p);
    prep_w2p<<<256, 256, 0, stream>>>(W2, W2p);
    gate_kernel<<<(T_TOK * E) / 256, 256, 0, stream>>>(x, Wg, bg, probs);
    moe_main<<<T_TOK / BM, 512, 0, stream>>>(x, W1p, b1, W2p, b2, probs, out);
}

// Round 19
// 216.949 us; speedup vs baseline: 1.3599x; 1.0220x over previous
//
#include <hip/hip_runtime.h>
#include <hip/hip_bf16.h>
#include <math.h>

#define H 256
#define F 512
#define E 8
#define T_TOK 32768
#define BM 128   // tokens per block
#define FC 64    // F-chunk size
#define NCH 64   // E * F/FC chunks

typedef float    f32x4 __attribute__((__ext_vector_type__(4)));
typedef _Float16 f16x8 __attribute__((__ext_vector_type__(8)));
typedef _Float16 f16x4 __attribute__((__ext_vector_type__(4)));

// lgkm-only barrier: publishes LDS (hs); register global loads stay in flight
#define BAR_LG() asm volatile("s_waitcnt lgkmcnt(0)\ns_barrier" ::: "memory")

// gelu(v) = v - v * rcp(1 + exp2(v*(c1 + c2*v^2)))   [tanh-approx]
__device__ __forceinline__ float gelu_fast(float v) {
    const float c1 = 2.302117236f;
    const float c2 = 0.102943842f;
    float u2 = v * fmaf(c2, v * v, c1);
    float ex = __builtin_amdgcn_exp2f(u2);
    float r = __builtin_amdgcn_rcpf(ex + 1.0f);
    return v - v * r;
}

// W1[e][h][f] fp32 -> W1p packed GEMM1 A-fragments.
// block blk = s*2 + fw  (s = e*8+c). frag g = ks*128 + pair*64 + lane.
// value[d] = W1[e][ks*32 + (lane>>4)*8 + d][c*64 + fw*32 + pair*16 + (lane&15)]
__global__ void prep_w1p(const float* __restrict__ in, _Float16* __restrict__ out) {
    __shared__ float t[256][33];
    int blk = blockIdx.x;          // 128
    int s = blk >> 1, fw = blk & 1;
    int e = s >> 3, c = s & 7;
    int f0 = c * 64 + fw * 32;
    int tid = threadIdx.x;         // 256
    int hr = tid >> 3, q = tid & 7;
#pragma unroll
    for (int pp = 0; pp < 8; ++pp) {
        int h = pp * 32 + hr;
        float4 v = *(const float4*)(in + ((size_t)e * H + h) * F + f0 + q * 4);
        t[h][q * 4 + 0] = v.x;
        t[h][q * 4 + 1] = v.y;
        t[h][q * 4 + 2] = v.z;
        t[h][q * 4 + 3] = v.w;
    }
    __syncthreads();
#pragma unroll
    for (int r = 0; r < 4; ++r) {
        int g = r * 256 + tid;
        int ks = g >> 7, pair = (g >> 6) & 1, ln = g & 63;
        int l4v = ln >> 4, l15v = ln & 15;
        f16x8 v;
#pragma unroll
        for (int d = 0; d < 8; ++d) v[d] = (_Float16)t[ks * 32 + l4v * 8 + d][pair * 16 + l15v];
        *(f16x8*)(out + ((size_t)blk * 1024 + g) * 8) = v;
    }
}

// W2[e][f][h] fp32 -> W2p packed GEMM2 A-fragments.
// chunk s=e*8+c; G = (hw*8 + i*2 + ks)*64 + lane
// value[d] = W2[e][c*64 + ks*32 + (lane>>4)*8 + d][hw*64 + i*16 + (lane&15)]
__global__ void prep_w2p(const float* __restrict__ in, _Float16* __restrict__ out) {
    __shared__ float t[64][65];
    int blk = blockIdx.x;         // 256
    int s = blk >> 2, hw = blk & 3;
    int e = s >> 3, c = s & 7;
    int tid = threadIdx.x;
    int fl = tid >> 2, h16 = (tid & 3) * 16;
    const float* ip = in + ((size_t)(e * F + c * 64 + fl)) * H + hw * 64 + h16;
#pragma unroll
    for (int q = 0; q < 4; ++q) {
        float4 v = *(const float4*)(ip + q * 4);
        t[fl][h16 + q * 4 + 0] = v.x;
        t[fl][h16 + q * 4 + 1] = v.y;
        t[fl][h16 + q * 4 + 2] = v.z;
        t[fl][h16 + q * 4 + 3] = v.w;
    }
    __syncthreads();
#pragma unroll
    for (int r = 0; r < 2; ++r) {
        int g = tid * 2 + r;
        int lane = g & 63, iks = g >> 6;
        int fb = (iks & 1) * 32 + (lane >> 4) * 8;
        int hl = (iks >> 1) * 16 + (lane & 15);
        f16x8 v;
#pragma unroll
        for (int d = 0; d < 8; ++d) v[d] = (_Float16)t[fb + d][hl];
        *(f16x8*)(out + (size_t)s * 16384 + ((size_t)hw * 512 + g) * 8) = v;
    }
}

__global__ void gate_kernel(const float* __restrict__ x, const float* __restrict__ Wg,
                            const float* __restrict__ bg, float* __restrict__ probs) {
    int gid = blockIdx.x * blockDim.x + threadIdx.x;
    int t = gid >> 3, e = gid & 7;
    const float* xr = x + (size_t)t * H;
    float acc = 0.f;
    for (int k = 0; k < H; k += 4) {
        float4 xv = *(const float4*)(xr + k);
        acc += xv.x * Wg[(k + 0) * E + e] + xv.y * Wg[(k + 1) * E + e]
             + xv.z * Wg[(k + 2) * E + e] + xv.w * Wg[(k + 3) * E + e];
    }
    acc += bg[e];
    float m = acc;
    for (int s = 1; s < 8; s <<= 1) m = fmaxf(m, __shfl_xor(m, s, 8));
    float p = expf(acc - m);
    float sum = p;
    for (int s = 1; s < 8; s <<= 1) sum += __shfl_xor(sum, s, 8);
    probs[gid] = p / sum;
}

// ---- main fused MoE FFN: 8 waves, LDS = hs only, all weights reg-loaded from L2
__global__ __launch_bounds__(512, 2) void moe_main(
    const float* __restrict__ x, const _Float16* __restrict__ W1p,
    const float* __restrict__ b1, const _Float16* __restrict__ W2p,
    const float* __restrict__ b2, const float* __restrict__ probs,
    float* __restrict__ out) {

    __shared__ __align__(16) _Float16 hs[2][BM * FC];  // 2 x 16 KB (32 KB total)

    int tid = threadIdx.x;
    int lane = tid & 63, wid = tid >> 6;
    int t0 = blockIdx.x * BM;
    int l15 = lane & 15, l4 = lane >> 4;

    int fw = wid >> 2, tw1 = wid & 3;   // GEMM1: 2(f-32) x 4(tok-32)
    int hw = wid >> 1, tw2 = wid & 1;   // GEMM2: 4(h-64) x 2(tok-64)

    // x B-fragments in registers (static, 64 VGPR)
    f16x8 xf[8][2];
#pragma unroll
    for (int j = 0; j < 2; ++j) {
        const float* xr = x + (size_t)(t0 + tw1 * 32 + j * 16 + l15) * H + (l4 << 3);
#pragma unroll
        for (int ks = 0; ks < 8; ++ks) {
            float4 v0 = *(const float4*)(xr + ks * 32);
            float4 v1 = *(const float4*)(xr + ks * 32 + 4);
            f16x8 hv;
            hv[0] = (_Float16)v0.x; hv[1] = (_Float16)v0.y; hv[2] = (_Float16)v0.z; hv[3] = (_Float16)v0.w;
            hv[4] = (_Float16)v1.x; hv[5] = (_Float16)v1.y; hv[6] = (_Float16)v1.z; hv[7] = (_Float16)v1.w;
            xf[ks][j] = hv;
        }
    }

    f32x4 yacc[4][4];
#pragma unroll
    for (int i = 0; i < 4; ++i)
#pragma unroll
        for (int j = 0; j < 4; ++j) yacc[i][j] = (f32x4){0.f, 0.f, 0.f, 0.f};

    float p0g = 0.f, p1g = 0.f;

    for (int s = 0; s < NCH; ++s) {
        int b = s & 1;
        int e = s >> 3, c = s & 7, fbase = c * FC;

        if ((s & 7) == 0) {  // new expert: reload gate probs for this wave's tok rows
            p0g = probs[(size_t)(t0 + tw1 * 32 + l15) * E + e];
            p1g = probs[(size_t)(t0 + tw1 * 32 + 16 + l15) * E + e];
        }

        const _Float16* w1b = W1p + ((size_t)(s * 2 + fw) * 1024 + lane) * 8;

        // (1) W1 fragment batch 1 (ks 0..3) + av (GEMM2 A) + b1 — all L2/L1-hot
        f16x8 w1a[4][2];
#pragma unroll
        for (int ks = 0; ks < 4; ++ks) {
            w1a[ks][0] = *(const f16x8*)(w1b + (ks * 2 + 0) * 512);
            w1a[ks][1] = *(const f16x8*)(w1b + (ks * 2 + 1) * 512);
        }
        f16x8 av[4][2];
        {
            const _Float16* wb = W2p + (size_t)s * 16384 + ((size_t)(hw * 8) * 64 + lane) * 8;
#pragma unroll
            for (int i = 0; i < 4; ++i) {
                av[i][0] = *(const f16x8*)(wb + (i * 2 + 0) * 512);
                av[i][1] = *(const f16x8*)(wb + (i * 2 + 1) * 512);
            }
        }
        float4 bvq[2];
#pragma unroll
        for (int i = 0; i < 2; ++i)
            bvq[i] = *(const float4*)(b1 + (size_t)e * F + fbase + (fw * 2 + i) * 16 + l4 * 4);

        // (2) GEMM1 part 1 (ks 0..3), then stream batch 2 (ks 4..7), part 2
        f32x4 hacc[2][2];
        hacc[0][0] = hacc[0][1] = hacc[1][0] = hacc[1][1] = (f32x4){0.f, 0.f, 0.f, 0.f};
#pragma unroll
        for (int ks = 0; ks < 4; ++ks) {
            hacc[0][0] = __builtin_amdgcn_mfma_f32_16x16x32_f16(w1a[ks][0], xf[ks][0], hacc[0][0], 0, 0, 0);
            hacc[0][1] = __builtin_amdgcn_mfma_f32_16x16x32_f16(w1a[ks][0], xf[ks][1], hacc[0][1], 0, 0, 0);
            hacc[1][0] = __builtin_amdgcn_mfma_f32_16x16x32_f16(w1a[ks][1], xf[ks][0], hacc[1][0], 0, 0, 0);
            hacc[1][1] = __builtin_amdgcn_mfma_f32_16x16x32_f16(w1a[ks][1], xf[ks][1], hacc[1][1], 0, 0, 0);
        }
#pragma unroll
        for (int ks = 0; ks < 4; ++ks) {
            w1a[ks][0] = *(const f16x8*)(w1b + ((ks + 4) * 2 + 0) * 512);
            w1a[ks][1] = *(const f16x8*)(w1b + ((ks + 4) * 2 + 1) * 512);
        }
#pragma unroll
        for (int ks = 0; ks < 4; ++ks) {
            hacc[0][0] = __builtin_amdgcn_mfma_f32_16x16x32_f16(w1a[ks][0], xf[ks + 4][0], hacc[0][0], 0, 0, 0);
            hacc[0][1] = __builtin_amdgcn_mfma_f32_16x16x32_f16(w1a[ks][0], xf[ks + 4][1], hacc[0][1], 0, 0, 0);
            hacc[1][0] = __builtin_amdgcn_mfma_f32_16x16x32_f16(w1a[ks][1], xf[ks + 4][0], hacc[1][0], 0, 0, 0);
            hacc[1][1] = __builtin_amdgcn_mfma_f32_16x16x32_f16(w1a[ks][1], xf[ks + 4][1], hacc[1][1], 0, 0, 0);
        }

        // (3) GELU + gate-fold -> hs[b]
#pragma unroll
        for (int i = 0; i < 2; ++i) {
            int flocal = (fw * 2 + i) * 16 + l4 * 4;
            float4 bv = bvq[i];
#pragma unroll
            for (int j = 0; j < 2; ++j) {
                int tokl = tw1 * 32 + j * 16 + l15;
                float p = j ? p1g : p0g;
                f32x4 hv = hacc[i][j];
                f16x4 hp;
                hp[0] = (_Float16)(p * gelu_fast(hv[0] + bv.x));
                hp[1] = (_Float16)(p * gelu_fast(hv[1] + bv.y));
                hp[2] = (_Float16)(p * gelu_fast(hv[2] + bv.z));
                hp[3] = (_Float16)(p * gelu_fast(hv[3] + bv.w));
                int idx = (tokl * FC + flocal) ^ ((tokl & 7) << 3);
                *(f16x4*)&hs[b][idx] = hp;
            }
        }

        // (4) the one barrier: hs[b] published (lgkm only; reg loads stay in flight)
        BAR_LG();

        // (5) GEMM2: y += W2chunk . hs[b]^T, K=FC (av in regs)
#pragma unroll
        for (int ks = 0; ks < FC / 32; ++ks) {
            int kidx = ks * 32 + (l4 << 3);
            f16x8 bv2[4];
#pragma unroll
            for (int j = 0; j < 4; ++j) {
                int tok = tw2 * 64 + j * 16 + l15;
                bv2[j] = *(const f16x8*)&hs[b][(tok * FC + kidx) ^ ((tok & 7) << 3)];
            }
#pragma unroll
            for (int i = 0; i < 4; ++i)
#pragma unroll
                for (int j = 0; j < 4; ++j)
                    yacc[i][j] = __builtin_amdgcn_mfma_f32_16x16x32_f16(av[i][ks], bv2[j], yacc[i][j], 0, 0, 0);
        }
        // next region writes hs[b^1]; hs[b] next written at s+2, after BAR(s+1) — safe
    }

    // epilogue: out = yacc + sum_e p_e * b2_e
#pragma unroll
    for (int j = 0; j < 4; ++j) {
        int tok = t0 + tw2 * 64 + j * 16 + l15;
        float pe[8];
#pragma unroll
        for (int e = 0; e < 8; ++e) pe[e] = probs[(size_t)tok * E + e];
#pragma unroll
        for (int i = 0; i < 4; ++i) {
            int h0 = hw * 64 + i * 16 + l4 * 4;
            f32x4 acc = yacc[i][j];
#pragma unroll
            for (int e = 0; e < 8; ++e) {
                float4 b2v = *(const float4*)(b2 + (size_t)e * H + h0);
                acc[0] += pe[e] * b2v.x;
                acc[1] += pe[e] * b2v.y;
                acc[2] += pe[e] * b2v.z;
                acc[3] += pe[e] * b2v.w;
            }
            *(f32x4*)(out + (size_t)tok * H + h0) = acc;
        }
    }
}

extern "C" void kernel_launch(void* const* d_in, const int* in_sizes, int n_in,
                              void* d_out, int out_size, void* d_ws, size_t ws_size,
                              hipStream_t stream) {
    const float* x  = (const float*)d_in[0];
    const float* Wg = (const float*)d_in[1];
    const float* bg = (const float*)d_in[2];
    const float* W1 = (const float*)d_in[3];
    const float* b1 = (const float*)d_in[4];
    const float* W2 = (const float*)d_in[5];
    const float* b2 = (const float*)d_in[6];
    float* out = (float*)d_out;

    _Float16* W1p = (_Float16*)d_ws;                       // packed GEMM1 frags, 2 MB
    _Float16* W2p = W1p + (size_t)E * F * H;               // packed GEMM2 frags, 2 MB
    float* probs  = (float*)(W2p + (size_t)64 * 16384);    // [T][E] fp32, 1 MB

    prep_w1p<<<128, 256, 0, stream>>>(W1, W1p);
    prep_w2p<<<256, 256, 0, stream>>>(W2, W2p);
    gate_kernel<<<(T_TOK * E) / 256, 256, 0, stream>>>(x, Wg, bg, probs);
    moe_main<<<T_TOK / BM, 512, 0, stream>>>(x, W1p, b1, W2p, b2, probs, out);
}